// Round 12
// baseline (92.102 us; speedup 1.0000x reference)
//
#include <hip/hip_runtime.h>
#include <hip/hip_bf16.h>
#include <math.h>

constexpr int B_  = 2048;
constexpr int S_  = 16;
constexpr int D_  = 512;
constexpr int CH_ = 1024;

typedef __attribute__((ext_vector_type(8))) short bf16x8;
typedef __attribute__((ext_vector_type(4))) float f32x4;

// ---------------- workspace layout ----------------
constexpr size_t CNT_OFF  = 0;                                  // 16 ints (64 B)
constexpr size_t NT_OFF   = 96;                                 // 1 int
constexpr size_t TL_OFF   = 128;                                // 64 ints
constexpr size_t LOG_OFF  = 384;                                // B*S floats = 128 KB
constexpr size_t LIST_OFF = LOG_OFF + (size_t)B_ * S_ * 4;      // 16*2048 ints = 128 KB
constexpr size_t XGT_OFF  = LIST_OFF + (size_t)16 * 2048 * 4;   // 2 MB bf16 [B][D]
constexpr size_t XGR_OFF  = XGT_OFF + (size_t)B_ * D_ * 2;      // 2 MB bf16 [B][D]

static __device__ __forceinline__ short f2bf(float x) {
    __hip_bfloat16 h = __float2bfloat16(x);
    return *(short*)&h;
}
static __device__ __forceinline__ float gelu_exact(float x) {
    return 0.5f * x * (1.f + erff(x * 0.70710678118654752f));
}
static __device__ __forceinline__ float dot4(float4 a, float4 b) {
    return a.x * b.x + a.y * b.y + a.z * b.z + a.w * b.w;
}

// async global -> LDS, 16 bytes per lane
static __device__ __forceinline__ void gl_lds16(const void* g, void* l) {
    __builtin_amdgcn_global_load_lds(
        (const __attribute__((address_space(1))) void*)g,
        (__attribute__((address_space(3))) void*)l,
        16, 0, 0);
}

// ---------------- kernel 1: persistent pipelined logits scan ----------------
// 4096 waves, 8 rows each; 2-deep ping-pong prefetch, no barriers, no LDS
__global__ __launch_bounds__(256, 4) void k_logits(
    const float* __restrict__ ldt, const float* __restrict__ ldr,
    const float* __restrict__ w,   const float* __restrict__ bsc,
    float* __restrict__ logits)
{
    const int lane = threadIdx.x & 63;
    const int wid  = blockIdx.x * 4 + (threadIdx.x >> 6);   // 0..4095

    const float4* wt = (const float4*)w;   // 256 float4: [0,128)=t, [128,256)=r
    const float4 wv0 = wt[lane];
    const float4 wv1 = wt[lane + 64];
    const float4 wv2 = wt[lane + 128];
    const float4 wv3 = wt[lane + 192];
    const float bias = bsc[0];

    float4 ca[4], cb[4];

#define LOADROW(row, v)                                                     \
    {                                                                       \
        const float4* pt_ = (const float4*)(ldt + (size_t)(row) * D_);      \
        const float4* pr_ = (const float4*)(ldr + (size_t)(row) * D_);      \
        v[0] = pt_[lane]; v[1] = pt_[lane + 64];                            \
        v[2] = pr_[lane]; v[3] = pr_[lane + 64];                            \
    }
#define REDUCEROW(row, v)                                                   \
    {                                                                       \
        float a_ = dot4(v[0], wv0) + dot4(v[1], wv1)                        \
                 + dot4(v[2], wv2) + dot4(v[3], wv3);                       \
        _Pragma("unroll")                                                   \
        for (int off_ = 32; off_ > 0; off_ >>= 1)                           \
            a_ += __shfl_down(a_, off_, 64);                                \
        if (lane == 0) logits[row] = a_ + bias;                             \
    }

    // rows: wid + k*4096, k = 0..7  (B*S = 32768 rows total)
    LOADROW(wid, ca)
    LOADROW(wid + 1 * 4096, cb)
    REDUCEROW(wid, ca)
    LOADROW(wid + 2 * 4096, ca)
    REDUCEROW(wid + 1 * 4096, cb)
    LOADROW(wid + 3 * 4096, cb)
    REDUCEROW(wid + 2 * 4096, ca)
    LOADROW(wid + 4 * 4096, ca)
    REDUCEROW(wid + 3 * 4096, cb)
    LOADROW(wid + 5 * 4096, cb)
    REDUCEROW(wid + 4 * 4096, ca)
    LOADROW(wid + 6 * 4096, ca)
    REDUCEROW(wid + 5 * 4096, cb)
    LOADROW(wid + 7 * 4096, cb)
    REDUCEROW(wid + 6 * 4096, ca)
    REDUCEROW(wid + 7 * 4096, cb)

#undef LOADROW
#undef REDUCEROW
}

// ---------------- kernel 2: softmax + argmax + compaction + gather ----------------
// wave = one sample; 4 samples per 256-thread block
__global__ __launch_bounds__(256) void k_finish(
    const float* __restrict__ ldt, const float* __restrict__ ldr,
    const float* __restrict__ logits,
    float* __restrict__ sld, int* __restrict__ count, int* __restrict__ list,
    unsigned short* __restrict__ xgt, unsigned short* __restrict__ xgr,
    float* __restrict__ pose)
{
    const int wave = threadIdx.x >> 6;
    const int lane = threadIdx.x & 63;
    const int b    = blockIdx.x * 4 + wave;

    float v = (lane < S_) ? logits[b * S_ + lane] : -INFINITY;
    float mv = v; int mi_ = lane;
    #pragma unroll
    for (int d = 1; d < 16; d <<= 1) {
        float ov = __shfl_xor(mv, d, 16);
        int   oi = __shfl_xor(mi_, d, 16);
        if (ov > mv || (ov == mv && oi < mi_)) { mv = ov; mi_ = oi; }
    }
    float e = (lane < S_) ? expf(v - mv) : 0.f;
    float sum = e;
    #pragma unroll
    for (int d = 1; d < 16; d <<= 1) sum += __shfl_xor(sum, d, 16);
    if (lane < S_) sld[b * S_ + lane] = v - (mv + logf(sum));

    const int mi = __shfl(mi_, 0, 64);
    if (lane == 0) {
        const int pos = atomicAdd(&count[mi], 1);
        list[mi * B_ + pos] = b;
    }
    if (lane < 7) pose[(size_t)b * 7 + lane] = 0.f;

    // gather selected rows -> compact bf16 (L3-hot)
    const float4* pt = (const float4*)(ldt + ((size_t)b * S_ + mi) * D_);
    const float4* pr = (const float4*)(ldr + ((size_t)b * S_ + mi) * D_);
    #pragma unroll
    for (int h = 0; h < 2; h++) {
        const int i = lane + h * 64;
        const float4 a = pt[i];
        short4 o1; o1.x = f2bf(a.x); o1.y = f2bf(a.y); o1.z = f2bf(a.z); o1.w = f2bf(a.w);
        *reinterpret_cast<short4*>(&xgt[(size_t)b * D_ + (size_t)i * 4]) = o1;
        const float4 c = pr[i];
        short4 o2; o2.x = f2bf(c.x); o2.y = f2bf(c.y); o2.z = f2bf(c.z); o2.w = f2bf(c.w);
        *reinterpret_cast<short4*>(&xgr[(size_t)b * D_ + (size_t)i * 4]) = o2;
    }
}

// ---------------- kernel 3: tile-list compaction ----------------
__global__ void k_tiles(const int* __restrict__ count, int* __restrict__ ntile,
                        int* __restrict__ tlist)
{
    if (threadIdx.x == 0 && blockIdx.x == 0) {
        int nt = 0;
        for (int m = 0; m < S_; m++) {
            const int c = count[m];
            const int nst = (c + 63) >> 6;
            for (int s2 = 0; s2 < nst; s2++) tlist[nt++] = m | (s2 << 8);
        }
        ntile[0] = nt;
    }
}

// ---------------- kernel 4: expert heads — global_load_lds staged MFMA ----------------
// bid = t(6) | head(1) | ct(4);  BM=64 x BN=64 x BK=64, 8 K-tiles
__global__ __launch_bounds__(256) void k_expert(
    const float* __restrict__ Wht, const float* __restrict__ bht,
    const float* __restrict__ Wot, const float* __restrict__ bot,
    const float* __restrict__ Whr, const float* __restrict__ bhr,
    const float* __restrict__ Wor, const float* __restrict__ bor,
    const unsigned short* __restrict__ xgt, const unsigned short* __restrict__ xgr,
    const int* __restrict__ count, const int* __restrict__ list,
    const int* __restrict__ ntile, const int* __restrict__ tlist,
    float* __restrict__ pose)
{
    const int bid  = blockIdx.x;
    const int ct   = bid & 15;
    const int head = (bid >> 4) & 1;
    const int t    = bid >> 5;
    if (t >= ntile[0]) return;
    const int tv = tlist[t];
    const int m  = tv & 255;
    const int st = tv >> 8;
    const int n  = count[m];

    const unsigned short* __restrict__ xg = head ? xgr : xgt;
    const float* __restrict__ Wh = head ? Whr : Wht;
    const float* __restrict__ bh = head ? bhr : bht;
    const float* __restrict__ Wo = head ? Wor : Wot;
    const float* __restrict__ bo = head ? bor : bot;
    const int noj    = head ? 4 : 3;
    const int jobase = head ? 3 : 0;
    const int ch0    = ct * 64;

    __shared__ short As[64 * 64];    //  8 KB bf16, source-swizzled k-chunks
    __shared__ float Bsf[64 * 64];   // 16 KB f32 linear [k][ch]
    __shared__ float ored[64][4];    //  1 KB
    __shared__ int   bidx[64];

    const int tid  = threadIdx.x;
    const int wave = tid >> 6;
    const int lane = tid & 63;
    const int l15  = lane & 15;
    const int lq   = lane >> 4;
    const int wr   = wave >> 1, wc = wave & 1;
    const int rbase = wr * 32, cbase = wc * 32;

    if (tid < 64) {
        const int gi = st * 64 + tid;
        bidx[tid] = (gi < n) ? list[m * B_ + gi] : list[m * B_];
    }
    ((float*)ored)[tid] = 0.f;
    __syncthreads();

    const unsigned short* gA[2];
    #pragma unroll
    for (int i = 0; i < 2; i++) {
        const int r = (wave * 2 + i) * 8 + (lane >> 3);
        const int c = (lane & 7) ^ (r & 7);
        gA[i] = xg + (size_t)bidx[r] * D_ + c * 8;
    }
    const float* gB[4];
    #pragma unroll
    for (int i = 0; i < 4; i++) {
        const int q2 = wave * 4 + i;
        gB[i] = Wh + (size_t)m * D_ * CH_ + (size_t)(q2 * 4 + (lane >> 4)) * CH_ + ch0 + (l15 * 4);
    }

    f32x4 acc[2][2] = {};

    for (int kt = 0; kt < 8; kt++) {
        const int k0 = kt * 64;
        #pragma unroll
        for (int i = 0; i < 2; i++)
            gl_lds16(gA[i] + k0, &As[(wave * 2 + i) * 512]);
        #pragma unroll
        for (int i = 0; i < 4; i++)
            gl_lds16(gB[i] + (size_t)k0 * CH_, &Bsf[(wave * 4 + i) * 256]);
        __syncthreads();

        #pragma unroll
        for (int ks = 0; ks < 2; ks++) {
            bf16x8 a[2];
            #pragma unroll
            for (int fm = 0; fm < 2; fm++) {
                const int r = rbase + fm * 16 + l15;
                const int u = ks * 4 + lq;
                a[fm] = *(const bf16x8*)&As[r * 64 + ((u ^ (r & 7)) << 3)];
            }
            bf16x8 bv[2];
            #pragma unroll
            for (int fn = 0; fn < 2; fn++) {
                const int c = cbase + fn * 16 + l15;
                const int kb = ks * 32 + lq * 8;
                short tmp[8];
                #pragma unroll
                for (int j = 0; j < 8; j++) tmp[j] = f2bf(Bsf[(kb + j) * 64 + c]);
                bv[fn] = *(bf16x8*)tmp;
            }
            #pragma unroll
            for (int fm = 0; fm < 2; fm++)
                #pragma unroll
                for (int fn = 0; fn < 2; fn++)
                    acc[fm][fn] = __builtin_amdgcn_mfma_f32_16x16x32_bf16(a[fm], bv[fn], acc[fm][fn], 0, 0, 0);
        }
        __syncthreads();
    }

    // ---- epilogue ----
    float g[2][2][4];
    float wo_l[2][4];
    #pragma unroll
    for (int fn = 0; fn < 2; fn++) {
        const int ch = ch0 + cbase + fn * 16 + l15;
        const float bias = bh[m * CH_ + ch];
        #pragma unroll
        for (int fm = 0; fm < 2; fm++)
            #pragma unroll
            for (int j = 0; j < 4; j++)
                g[fm][fn][j] = gelu_exact(acc[fm][fn][j] + bias);
        #pragma unroll
        for (int jo = 0; jo < 4; jo++)
            wo_l[fn][jo] = (jo < noj) ? Wo[(size_t)(m * CH_ + ch) * noj + jo] : 0.f;
    }

    #pragma unroll
    for (int fm = 0; fm < 2; fm++) {
        #pragma unroll
        for (int j = 0; j < 4; j++) {
            const int rl = rbase + fm * 16 + lq * 4 + j;
            #pragma unroll
            for (int jo = 0; jo < 4; jo++) {
                if (jo >= noj) continue;
                float v = g[fm][0][j] * wo_l[0][jo] + g[fm][1][j] * wo_l[1][jo];
                #pragma unroll
                for (int d = 1; d < 16; d <<= 1) v += __shfl_xor(v, d, 16);
                if (l15 == 0)
                    atomicAdd(&ored[rl][jo], v);
            }
        }
    }
    __syncthreads();

    {
        const int rl = tid >> 2;
        const int jo = tid & 3;
        const int gi = st * 64 + rl;
        if (jo < noj && gi < n) {
            const int bb = list[m * B_ + gi];
            float v = ored[rl][jo];
            if (ct == 0) v += bo[m * noj + jo];
            atomicAdd(&pose[(size_t)bb * 7 + jobase + jo], v);
        }
    }
}

// ---------------- launch ----------------
extern "C" void kernel_launch(void* const* d_in, const int* in_sizes, int n_in,
                              void* d_out, int out_size, void* d_ws, size_t ws_size,
                              hipStream_t stream)
{
    const float* ldt = (const float*)d_in[0];
    const float* ldr = (const float*)d_in[1];
    const float* wsc = (const float*)d_in[2];
    const float* bsc = (const float*)d_in[3];
    const float* Wht = (const float*)d_in[4];
    const float* bht = (const float*)d_in[5];
    const float* Wot = (const float*)d_in[6];
    const float* bot = (const float*)d_in[7];
    const float* Whr = (const float*)d_in[8];
    const float* bhr = (const float*)d_in[9];
    const float* Wor = (const float*)d_in[10];
    const float* bor = (const float*)d_in[11];

    float* pose = (float*)d_out;                   // [B,7]
    float* sld  = (float*)d_out + (size_t)B_ * 7;  // [B,16]

    int*   count  = (int*)((char*)d_ws + CNT_OFF);
    int*   ntile  = (int*)((char*)d_ws + NT_OFF);
    int*   tlist  = (int*)((char*)d_ws + TL_OFF);
    float* logits = (float*)((char*)d_ws + LOG_OFF);
    int*   list   = (int*)((char*)d_ws + LIST_OFF);
    unsigned short* xgt = (unsigned short*)((char*)d_ws + XGT_OFF);
    unsigned short* xgr = (unsigned short*)((char*)d_ws + XGR_OFF);

    (void)hipMemsetAsync(count, 0, 64, stream);

    // 1) persistent pipelined logits scan: 1024 blocks, 8 rows/wave
    k_logits<<<dim3(1024), dim3(256), 0, stream>>>(ldt, ldr, wsc, bsc, logits);

    // 2) softmax + argmax + compaction + gather
    k_finish<<<dim3(B_ / 4), dim3(256), 0, stream>>>(
        ldt, ldr, logits, sld, count, list, xgt, xgr, pose);

    // 3) compact tile list
    k_tiles<<<dim3(1), dim3(64), 0, stream>>>(count, ntile, tlist);

    // 4) expert heads: grid = 48 tile slots x 2 heads x 16 ch-stripes
    k_expert<<<dim3(48 * 2 * 16), dim3(256), 0, stream>>>(
        Wht, bht, Wot, bot, Whr, bhr, Wor, bor,
        xgt, xgr, count, list, ntile, tlist, pose);
}